// Round 8
// baseline (245.650 us; speedup 1.0000x reference)
//
#include <hip/hip_runtime.h>

typedef _Float16 half2v __attribute__((ext_vector_type(2)));

// ---- w_span fp32 -> fp16 (feeds k_main's v_dot2 path); block 0 zeroes stats ----
__global__ void k_prep(const float* __restrict__ wspan, _Float16* __restrict__ w16,
                       float* __restrict__ stats){
  int i = blockIdx.x * 256 + threadIdx.x;
  if (i < 12544) w16[i] = (_Float16)wspan[i];
  if (blockIdx.x == 0 && threadIdx.x < 32) stats[threadIdx.x] = 0.f;
}

// ---- fused front-end v3: dw3x3 + pw1x1 + reduce1x1 + BN stats ----
// 8x8 px tile, 1024 blocks. Single staging round (all 64 ch), 2 barriers total.
// wave w: dw for c4-groups {w,4+w,8+w,12+w}; pw outputs 16w..16w+15; red 4w..4w+3.
__launch_bounds__(256, 3)
__global__ void k_front(const float* __restrict__ in, const float* __restrict__ wdw,
                        const float* __restrict__ wpw, const float* __restrict__ wred,
                        float* __restrict__ h, float* __restrict__ r,
                        float* __restrict__ stats){
  __shared__ float4 s_in4[16][10][12];               // [c4][ry][rx], 30.7 KB
  __shared__ float4 s_dw4[16][64];                   // [c4][px], 16 KB
  __shared__ float  s_red[4][8];
  int t = threadIdx.x;
  int w = t >> 6, lane = t & 63;
  int lx = lane & 7, ly = lane >> 3;
  int blk = blockIdx.x;
  int tile = blk & 255, b = blk >> 8;
  int x0 = (tile & 15) << 3, y0 = (tile >> 4) << 3;
  const float* inb = in + ((long)b << 20);

  // ---- stage: 16 c4-groups x 10x10 halo, all loads in flight at once ----
  for (int i = t; i < 1600; i += 256){
    int c4 = i / 100, pos = i - c4 * 100;
    int ry = pos / 10, rx = pos - ry * 10;
    int yy = y0 + ry - 1, xx = x0 + rx - 1;
    float4 v = make_float4(0.f, 0.f, 0.f, 0.f);
    if ((unsigned)yy < 128u && (unsigned)xx < 128u){
      long base = ((long)(c4 << 2) << 14) + (yy << 7) + xx;
      v.x = inb[base];
      v.y = inb[base + 16384];
      v.z = inb[base + 32768];
      v.w = inb[base + 49152];
    }
    s_in4[c4][ry][rx] = v;
  }
  __syncthreads();

  // ---- dw: wave w convolves groups w, 4+w, 8+w, 12+w (once per px) ----
  #pragma unroll
  for (int j = 0; j < 4; j++){
    int g = (j << 2) + w;
    const float* wd = wdw + (g << 2) * 9;            // uniform -> s_load
    float4 a = make_float4(0.f, 0.f, 0.f, 0.f);
    #pragma unroll
    for (int dy = 0; dy < 3; dy++){
      #pragma unroll
      for (int dx = 0; dx < 3; dx++){
        float4 v = s_in4[g][ly + dy][lx + dx];
        int k = dy * 3 + dx;
        a.x += v.x * wd[k];
        a.y += v.y * wd[9 + k];
        a.z += v.z * wd[18 + k];
        a.w += v.w * wd[27 + k];
      }
    }
    s_dw4[g][lane] = a;
  }
  __syncthreads();

  // ---- pw + red accumulate over all 16 groups ----
  float pacc[16], racc[4];
  #pragma unroll
  for (int j = 0; j < 16; j++) pacc[j] = 0.f;
  #pragma unroll
  for (int j = 0; j < 4; j++) racc[j] = 0.f;
  #pragma unroll 4
  for (int g = 0; g < 16; g++){
    float4 d  = s_dw4[g][lane];
    float4 cv = s_in4[g][ly + 1][lx + 1];            // raw center for reduce
    int c0 = g << 2;
    #pragma unroll
    for (int j = 0; j < 16; j++){
      const float* wr = wpw + ((w << 4) + j) * 64 + c0;  // uniform -> s_load
      pacc[j] += d.x * wr[0] + d.y * wr[1] + d.z * wr[2] + d.w * wr[3];
    }
    #pragma unroll
    for (int j = 0; j < 4; j++){
      const float* wr = wred + ((w << 2) + j) * 64 + c0;
      racc[j] += cv.x * wr[0] + cv.y * wr[1] + cv.z * wr[2] + cv.w * wr[3];
    }
  }

  long sp = ((long)(y0 + ly) << 7) + x0 + lx;
  float* hb = h + ((long)b << 20) + sp;
  #pragma unroll
  for (int j = 0; j < 16; j++) hb[(long)((w << 4) + j) << 14] = pacc[j];
  float* rb = r + ((long)b << 18) + sp;
  #pragma unroll
  for (int j = 0; j < 4; j++) rb[(long)((w << 2) + j) << 14] = racc[j];

  // ---- BN stats: wave w owns channels 4w..4w+3 ----
  #pragma unroll
  for (int j = 0; j < 4; j++){
    float v = racc[j], s2 = racc[j] * racc[j];
    #pragma unroll
    for (int off = 32; off > 0; off >>= 1){
      v  += __shfl_down(v,  off, 64);
      s2 += __shfl_down(s2, off, 64);
    }
    if (lane == 0){ s_red[w][2 * j] = v; s_red[w][2 * j + 1] = s2; }
  }
  __syncthreads();
  if (t < 32) atomicAdd(&stats[t], s_red[t >> 3][t & 7]);
}

// ---- BN finalize: scale/bias per channel (training-mode, biased var) ----
__global__ void k_bn(const float* __restrict__ stats, const float* __restrict__ gamma,
                     const float* __restrict__ beta, float* __restrict__ sb){
  int c = threadIdx.x;
  if (c < 16){
    const float n = 65536.f;                         // B*H*W
    float mean = stats[2 * c] / n;
    float var  = stats[2 * c + 1] / n - mean * mean;
    float inv  = rsqrtf(var + 1e-5f);
    float sc   = gamma[c] * inv;
    sb[2 * c]     = sc;
    sb[2 * c + 1] = beta[c] - mean * sc;
  }
}

// ---- main involution: per (b, g, 16x16 tile); kern-gen via v_dot2_f32_f16 ----
__launch_bounds__(256)
__global__ void k_main(const float* __restrict__ h, const float* __restrict__ r,
                       const float* __restrict__ sb, const _Float16* __restrict__ w16,
                       float* __restrict__ out){
  __shared__ float4 s_h4[22][24];                    // [row][col] -> 4 cg contiguous
  int t = threadIdx.x;
  int g = blockIdx.y, b = blockIdx.z;
  int tx0 = (blockIdx.x & 7) << 4, ty0 = (blockIdx.x >> 3) << 4;

  const float* hp = h + (((long)(b * 64 + g * 4)) << 14);
  for (int p = t; p < 484; p += 256){                // 22x22 halo points
    int ry = p / 22, rx = p - ry * 22;
    int yy = ty0 + ry - 3, xx = tx0 + rx - 3;
    float4 v = make_float4(0.f, 0.f, 0.f, 0.f);
    if ((unsigned)yy < 128u && (unsigned)xx < 128u){
      int o = (yy << 7) + xx;
      v.x = hp[o];
      v.y = hp[o + 16384];
      v.z = hp[o + 32768];
      v.w = hp[o + 49152];
    }
    s_h4[ry][rx] = v;
  }

  int ltx = t & 15, lty = t >> 4;
  int px = tx0 + ltx, py = ty0 + lty;
  const float* rp = r + ((long)b << 18) + (py << 7) + px;
  float rv[16];
  #pragma unroll
  for (int c = 0; c < 16; c++){
    float v = rp[(long)c << 14];
    rv[c] = fmaxf(v * sb[2 * c] + sb[2 * c + 1], 0.f);
  }
#if __has_builtin(__builtin_amdgcn_fdot2)
  half2v rv2[8];
  #pragma unroll
  for (int j = 0; j < 8; j++){
    half2v pk; pk[0] = (_Float16)rv[2 * j]; pk[1] = (_Float16)rv[2 * j + 1];
    rv2[j] = pk;
  }
#endif
  __syncthreads();

  const _Float16* wg = w16 + g * 784;                // uniform -> scalar pipe
#if __has_builtin(__builtin_amdgcn_fdot2)
  const half2v* wg2 = (const half2v*)wg;
#endif
  float acc0 = 0.f, acc1 = 0.f, acc2 = 0.f, acc3 = 0.f;
  #pragma unroll
  for (int kh = 0; kh < 7; kh++){
    #pragma unroll
    for (int kw = 0; kw < 7; kw++){
      int k = kh * 7 + kw;
      float kv = 0.f;
#if __has_builtin(__builtin_amdgcn_fdot2)
      #pragma unroll
      for (int j = 0; j < 8; j++)
        kv = __builtin_amdgcn_fdot2(rv2[j], wg2[k * 8 + j], kv, false);
#else
      #pragma unroll
      for (int c = 0; c < 16; c++) kv += rv[c] * (float)wg[k * 16 + c];
#endif
      float4 hv = s_h4[lty + kh][ltx + kw];
      acc0 += kv * hv.x;
      acc1 += kv * hv.y;
      acc2 += kv * hv.z;
      acc3 += kv * hv.w;
    }
  }

  long obase = (((long)(b * 64 + g * 4)) << 14) + (py << 7) + px;
  out[obase]         = acc0;
  out[obase + 16384] = acc1;
  out[obase + 32768] = acc2;
  out[obase + 49152] = acc3;
}

extern "C" void kernel_launch(void* const* d_in, const int* in_sizes, int n_in,
                              void* d_out, int out_size, void* d_ws, size_t ws_size,
                              hipStream_t stream){
  const float* in       = (const float*)d_in[0];
  const float* w_dw     = (const float*)d_in[1];
  const float* w_pw     = (const float*)d_in[2];
  const float* gamma    = (const float*)d_in[3];
  const float* beta     = (const float*)d_in[4];
  const float* w_reduce = (const float*)d_in[5];
  const float* w_span   = (const float*)d_in[6];
  float* out = (float*)d_out;

  float* ws    = (float*)d_ws;
  float* h     = ws;                    // 4194304 floats
  float* r     = ws + 4194304;          // 1048576 floats
  float* stats = ws + 5242880;          // 32 floats
  float* sb    = ws + 5242912;          // 32 floats
  _Float16* w16 = (_Float16*)(ws + 5242944);  // 12544 halfs

  k_prep <<<49, 256, 0, stream>>>(w_span, w16, stats);
  k_front<<<1024, 256, 0, stream>>>(in, w_dw, w_pw, w_reduce, h, r, stats);
  k_bn   <<<1, 16, 0, stream>>>(stats, gamma, beta, sb);
  dim3 grid(64, 16, 4);
  k_main <<<grid, 256, 0, stream>>>(h, r, sb, w16, out);
}

// Round 9
// 171.393 us; speedup vs baseline: 1.4333x; 1.4333x over previous
//
#include <hip/hip_runtime.h>

// ---- zero small stats buffer (ws is poisoned 0xAA each call) ----
__global__ void k_zero(float* __restrict__ p, int n){
  int i = blockIdx.x * blockDim.x + threadIdx.x;
  if (i < n) p[i] = 0.f;
}

// ---- fused front-end v2 (proven 61us): dw3x3 + pw1x1 + reduce1x1 + BN stats ----
// 8x8 px tile, 1024 blocks (4/CU). wave = full tile (lane=px).
// Per 16-ch chunk: all stage -> wave w dw-convs its 4 channels -> LDS ->
// wave w accumulates pw outputs 16w..16w+15 and red ch 4w..4w+3.
__launch_bounds__(256, 4)
__global__ void k_front(const float* __restrict__ in, const float* __restrict__ wdw,
                        const float* __restrict__ wpw, const float* __restrict__ wred,
                        float* __restrict__ h, float* __restrict__ r,
                        float* __restrict__ stats){
  __shared__ float4 s_in4[4][10][12];                // [c4][ry][rx] 4ch contiguous
  __shared__ float4 s_dw4[4][64];                    // [c4][px]
  __shared__ float4 s_cv4[4][64];                    // [c4][px] raw center vals
  __shared__ float  s_red[4][8];
  int t = threadIdx.x;
  int w = t >> 6, lane = t & 63;
  int lx = lane & 7, ly = lane >> 3;
  int blk = blockIdx.x;
  int tile = blk & 255, b = blk >> 8;
  int x0 = (tile & 15) << 3, y0 = (tile >> 4) << 3;
  const float* inb = in + ((long)b << 20);

  float pacc[16], racc[4];
  #pragma unroll
  for (int j = 0; j < 16; j++) pacc[j] = 0.f;
  #pragma unroll
  for (int j = 0; j < 4; j++) racc[j] = 0.f;

  for (int q = 0; q < 4; q++){
    int c0 = q << 4;
    __syncthreads();                                 // s_in4 free (prev dw done)
    for (int i = t; i < 400; i += 256){              // 4 c4-groups x 10x10 halo
      int c4 = i / 100, pos = i - c4 * 100;
      int ry = pos / 10, rx = pos - ry * 10;
      int yy = y0 + ry - 1, xx = x0 + rx - 1;
      float4 v = make_float4(0.f, 0.f, 0.f, 0.f);
      if ((unsigned)yy < 128u && (unsigned)xx < 128u){
        long base = ((long)(c0 + (c4 << 2)) << 14) + (yy << 7) + xx;
        v.x = inb[base];
        v.y = inb[base + 16384];
        v.z = inb[base + 32768];
        v.w = inb[base + 49152];
      }
      s_in4[c4][ry][rx] = v;
    }
    __syncthreads();

    // dw: wave w convolves its 4 channels (c0+4w .. +3), once per px
    {
      const float* wd = wdw + (c0 + (w << 2)) * 9;   // uniform -> s_load
      float4 a = make_float4(0.f, 0.f, 0.f, 0.f);
      float4 cv = make_float4(0.f, 0.f, 0.f, 0.f);
      #pragma unroll
      for (int dy = 0; dy < 3; dy++){
        #pragma unroll
        for (int dx = 0; dx < 3; dx++){
          float4 v = s_in4[w][ly + dy][lx + dx];
          int k = dy * 3 + dx;
          a.x += v.x * wd[k];
          a.y += v.y * wd[9 + k];
          a.z += v.z * wd[18 + k];
          a.w += v.w * wd[27 + k];
          if (k == 4) cv = v;
        }
      }
      s_dw4[w][lane] = a;
      s_cv4[w][lane] = cv;
    }
    __syncthreads();

    float4 d0 = s_dw4[0][lane], d1 = s_dw4[1][lane];
    float4 d2 = s_dw4[2][lane], d3 = s_dw4[3][lane];
    float4 e0 = s_cv4[0][lane], e1 = s_cv4[1][lane];
    float4 e2 = s_cv4[2][lane], e3 = s_cv4[3][lane];
    #pragma unroll
    for (int j = 0; j < 16; j++){
      const float* wr = wpw + ((w << 4) + j) * 64 + c0;  // uniform -> s_load
      float s = pacc[j];
      s += d0.x * wr[0]  + d0.y * wr[1]  + d0.z * wr[2]  + d0.w * wr[3];
      s += d1.x * wr[4]  + d1.y * wr[5]  + d1.z * wr[6]  + d1.w * wr[7];
      s += d2.x * wr[8]  + d2.y * wr[9]  + d2.z * wr[10] + d2.w * wr[11];
      s += d3.x * wr[12] + d3.y * wr[13] + d3.z * wr[14] + d3.w * wr[15];
      pacc[j] = s;
    }
    #pragma unroll
    for (int j = 0; j < 4; j++){
      const float* wr = wred + ((w << 2) + j) * 64 + c0;
      float s = racc[j];
      s += e0.x * wr[0]  + e0.y * wr[1]  + e0.z * wr[2]  + e0.w * wr[3];
      s += e1.x * wr[4]  + e1.y * wr[5]  + e1.z * wr[6]  + e1.w * wr[7];
      s += e2.x * wr[8]  + e2.y * wr[9]  + e2.z * wr[10] + e2.w * wr[11];
      s += e3.x * wr[12] + e3.y * wr[13] + e3.z * wr[14] + e3.w * wr[15];
      racc[j] = s;
    }
  }

  long sp = ((long)(y0 + ly) << 7) + x0 + lx;
  float* hb = h + ((long)b << 20) + sp;
  #pragma unroll
  for (int j = 0; j < 16; j++) hb[(long)((w << 4) + j) << 14] = pacc[j];
  float* rb = r + ((long)b << 18) + sp;
  #pragma unroll
  for (int j = 0; j < 4; j++) rb[(long)((w << 2) + j) << 14] = racc[j];

  // BN stats: wave w owns channels 4w..4w+3
  #pragma unroll
  for (int j = 0; j < 4; j++){
    float v = racc[j], s2 = racc[j] * racc[j];
    #pragma unroll
    for (int off = 32; off > 0; off >>= 1){
      v  += __shfl_down(v,  off, 64);
      s2 += __shfl_down(s2, off, 64);
    }
    if (lane == 0){ s_red[w][2 * j] = v; s_red[w][2 * j + 1] = s2; }
  }
  __syncthreads();
  if (t < 32) atomicAdd(&stats[t], s_red[t >> 3][t & 7]);
}

// ---- BN finalize: scale/bias per channel (training-mode, biased var) ----
__global__ void k_bn(const float* __restrict__ stats, const float* __restrict__ gamma,
                     const float* __restrict__ beta, float* __restrict__ sb){
  int c = threadIdx.x;
  if (c < 16){
    const float n = 65536.f;                         // B*H*W
    float mean = stats[2 * c] / n;
    float var  = stats[2 * c + 1] / n - mean * mean;
    float inv  = rsqrtf(var + 1e-5f);
    float sc   = gamma[c] * inv;
    sb[2 * c]     = sc;
    sb[2 * c + 1] = beta[c] - mean * sc;
  }
}

// ---- main involution (proven 46us): per (b, g, 16x16 tile) ----
// fp32 kern-gen with wave-uniform wspan reads -> scalar-pipe s_loads
__launch_bounds__(256)
__global__ void k_main(const float* __restrict__ h, const float* __restrict__ r,
                       const float* __restrict__ sb, const float* __restrict__ wspan,
                       float* __restrict__ out){
  __shared__ float4 s_h4[22][24];                    // [row][col] -> 4 cg contiguous
  int t = threadIdx.x;
  int g = blockIdx.y, b = blockIdx.z;
  int tx0 = (blockIdx.x & 7) << 4, ty0 = (blockIdx.x >> 3) << 4;

  const float* hp = h + (((long)(b * 64 + g * 4)) << 14);
  for (int p = t; p < 484; p += 256){                // 22x22 halo points
    int ry = p / 22, rx = p - ry * 22;
    int yy = ty0 + ry - 3, xx = tx0 + rx - 3;
    float4 v = make_float4(0.f, 0.f, 0.f, 0.f);
    if ((unsigned)yy < 128u && (unsigned)xx < 128u){
      int o = (yy << 7) + xx;
      v.x = hp[o];
      v.y = hp[o + 16384];
      v.z = hp[o + 32768];
      v.w = hp[o + 49152];
    }
    s_h4[ry][rx] = v;
  }

  int ltx = t & 15, lty = t >> 4;
  int px = tx0 + ltx, py = ty0 + lty;
  const float* rp = r + ((long)b << 18) + (py << 7) + px;
  float rv[16];
  #pragma unroll
  for (int c = 0; c < 16; c++){
    float v = rp[(long)c << 14];
    rv[c] = fmaxf(v * sb[2 * c] + sb[2 * c + 1], 0.f);
  }
  __syncthreads();

  // fused kern-gen + conv: per tap, 16 FMA (kern) + 1 b128 + 4 FMA (conv)
  const float* wsp = wspan + g * 784;                // uniform -> scalar pipe
  float acc0 = 0.f, acc1 = 0.f, acc2 = 0.f, acc3 = 0.f;
  #pragma unroll
  for (int kh = 0; kh < 7; kh++){
    #pragma unroll
    for (int kw = 0; kw < 7; kw++){
      int k = kh * 7 + kw;
      float kv = 0.f;
      #pragma unroll
      for (int c = 0; c < 16; c++) kv += rv[c] * wsp[k * 16 + c];
      float4 hv = s_h4[lty + kh][ltx + kw];
      acc0 += kv * hv.x;
      acc1 += kv * hv.y;
      acc2 += kv * hv.z;
      acc3 += kv * hv.w;
    }
  }

  long obase = (((long)(b * 64 + g * 4)) << 14) + (py << 7) + px;
  out[obase]         = acc0;
  out[obase + 16384] = acc1;
  out[obase + 32768] = acc2;
  out[obase + 49152] = acc3;
}

extern "C" void kernel_launch(void* const* d_in, const int* in_sizes, int n_in,
                              void* d_out, int out_size, void* d_ws, size_t ws_size,
                              hipStream_t stream){
  const float* in       = (const float*)d_in[0];
  const float* w_dw     = (const float*)d_in[1];
  const float* w_pw     = (const float*)d_in[2];
  const float* gamma    = (const float*)d_in[3];
  const float* beta     = (const float*)d_in[4];
  const float* w_reduce = (const float*)d_in[5];
  const float* w_span   = (const float*)d_in[6];
  float* out = (float*)d_out;

  float* ws    = (float*)d_ws;
  float* h     = ws;                    // 4194304 floats
  float* r     = ws + 4194304;          // 1048576 floats
  float* stats = ws + 5242880;          // 32 floats
  float* sb    = ws + 5242912;          // 32 floats

  k_zero <<<1, 64, 0, stream>>>(stats, 32);
  k_front<<<1024, 256, 0, stream>>>(in, w_dw, w_pw, w_reduce, h, r, stats);
  k_bn   <<<1, 16, 0, stream>>>(stats, gamma, beta, sb);
  dim3 grid(64, 16, 4);
  k_main <<<grid, 256, 0, stream>>>(h, r, sb, w_span, out);
}